// Round 8
// baseline (483.910 us; speedup 1.0000x reference)
//
#include <hip/hip_runtime.h>
#include <hip/hip_bf16.h>
#include <stdint.h>

typedef __attribute__((ext_vector_type(8))) short short8;
typedef __attribute__((ext_vector_type(4))) float f32x4;

#define N_NODES 16384
#define D_IN    512
#define D_HID   256
#define D_OUT   64
#define S_SAMP  4096

__device__ __forceinline__ unsigned short f2bf(float f) {
  __hip_bfloat16 h = __float2bfloat16(f);
  union { __hip_bfloat16 h; unsigned short u; } cv; cv.h = h; return cv.u;
}

// ---------------------------------------------------------------------------
// gemm_tn — R2 baseline structure (single-buffered As/Bs, BK=64, two barriers
// per K-step, mt-major, atomic split-K output) + optional fused finalize:
//   FIN=0: none (gemm4)
//   FIN=1: last kc-block per mt: bias+relu+scatter C-tile -> dstT   (gemm1)
//   FIN=2: last kc-block per mt: relu(C-tile) @ W2t + b2, relu, scatter -> dstT
//          (fuses gemm3 + its scatter into gemm2)
// ---------------------------------------------------------------------------
template<int BM, int BN, int BK, bool RELU_A, int FIN>
__global__ __launch_bounds__(256, FIN ? 4 : 1)
void gemm_tn(const float* __restrict__ A, int lda,
             const int* __restrict__ arow,
             const unsigned short* __restrict__ Bt, int ldb,
             float* __restrict__ C, int ldc,
             int K, int kChunks, float scale,
             const float* __restrict__ bias, const int* __restrict__ rows,
             unsigned short* __restrict__ dstT, const unsigned short* __restrict__ W2t,
             int* __restrict__ cnt)
{
  static_assert(BM == 64 && BK == 64 && (BN == 64 || BN == 256), "tile");
  constexpr int CH    = BK / 8;
  constexpr int RPS   = 512 / BK;
  constexpr int SLABS = BN / RPS;
  constexpr int SLABW = SLABS / 4;

  const int mt  = blockIdx.x / kChunks;
  const int kc  = blockIdx.x % kChunks;
  const int kLen = K / kChunks;
  const int k0   = kc * kLen;
  const int tid  = threadIdx.x;
  const int lane = tid & 63;
  const int wid  = tid >> 6;
  const int l16  = lane & 15;
  const int lg   = lane >> 4;

  __shared__ unsigned short As[BM * BK];
  __shared__ unsigned short Bs[BN * BK];
  __shared__ int s_done;

  constexpr int WN  = (BN == 256) ? 4 : 2;
  constexpr int WM  = 4 / WN;
  constexpr int WTM = BM / WM;
  constexpr int WTN = BN / WN;
  constexpr int MF  = WTM / 16;
  constexpr int NF  = WTN / 16;
  const int wrow = wid / WN;
  const int wcol = wid % WN;

  f32x4 acc[MF][NF] = {};

  const int am   = tid >> 2;
  const int aseg = tid & 3;
  const int arowIdx = mt * BM + am;
  const size_t rowg = arow ? (size_t)arow[arowIdx] : (size_t)arowIdx;
  const float* aBase = A + rowg * (size_t)lda + k0 + aseg * 16;

  const int brow = lane / CH;
  const int bcol = 8 * ((lane % CH) ^ (brow & (CH - 1)));
  const unsigned short* bSrc = Bt + (size_t)brow * ldb + k0 + bcol;

  for (int ks = 0; ks < kLen; ks += BK) {
    __syncthreads();
    // ---- issue B loads (async, no VGPR round-trip) ----
    #pragma unroll
    for (int i = 0; i < SLABW; ++i) {
      const int s = wid * SLABW + i;
      __builtin_amdgcn_global_load_lds(
          (const __attribute__((address_space(1))) uint32_t*)(bSrc + (size_t)s * RPS * ldb + ks),
          (__attribute__((address_space(3))) uint32_t*)(&Bs[s * 512]),
          16, 0, 0);
    }
    // ---- stage A: f32 -> bf16, swizzled 16B chunks ----
    {
      const float* ap = aBase + ks;
      f32x4 v0 = *(const f32x4*)(ap + 0);
      f32x4 v1 = *(const f32x4*)(ap + 4);
      f32x4 v2 = *(const f32x4*)(ap + 8);
      f32x4 v3 = *(const f32x4*)(ap + 12);
      if (RELU_A) {
        #pragma unroll
        for (int j = 0; j < 4; ++j) {
          v0[j] = fmaxf(v0[j], 0.f); v1[j] = fmaxf(v1[j], 0.f);
          v2[j] = fmaxf(v2[j], 0.f); v3[j] = fmaxf(v3[j], 0.f);
        }
      }
      short8 s0, s1;
      s0[0]=f2bf(v0[0]); s0[1]=f2bf(v0[1]); s0[2]=f2bf(v0[2]); s0[3]=f2bf(v0[3]);
      s0[4]=f2bf(v1[0]); s0[5]=f2bf(v1[1]); s0[6]=f2bf(v1[2]); s0[7]=f2bf(v1[3]);
      s1[0]=f2bf(v2[0]); s1[1]=f2bf(v2[1]); s1[2]=f2bf(v2[2]); s1[3]=f2bf(v2[3]);
      s1[4]=f2bf(v3[0]); s1[5]=f2bf(v3[1]); s1[6]=f2bf(v3[2]); s1[7]=f2bf(v3[3]);
      const int g0 = (aseg * 2)     ^ (am & 7);
      const int g1 = (aseg * 2 + 1) ^ (am & 7);
      *(short8*)&As[am * BK + g0 * 8] = s0;
      *(short8*)&As[am * BK + g1 * 8] = s1;
    }
    __syncthreads();
    // ---- compute ----
    #pragma unroll
    for (int kk = 0; kk < BK / 32; ++kk) {
      const int gk = kk * 4 + lg;
      short8 af[MF], bfr[NF];
      #pragma unroll
      for (int fm = 0; fm < MF; ++fm) {
        const int m = wrow * WTM + fm * 16 + l16;
        af[fm] = *(const short8*)&As[m * BK + ((gk ^ (m & 7)) * 8)];
      }
      #pragma unroll
      for (int fn = 0; fn < NF; ++fn) {
        const int n = wcol * WTN + fn * 16 + l16;
        bfr[fn] = *(const short8*)&Bs[n * BK + ((gk ^ (n & 7)) * 8)];
      }
      #pragma unroll
      for (int fm = 0; fm < MF; ++fm)
        #pragma unroll
        for (int fn = 0; fn < NF; ++fn)
          acc[fm][fn] = __builtin_amdgcn_mfma_f32_16x16x32_bf16(
              af[fm], bfr[fn], acc[fm][fn], 0, 0, 0);
    }
  }
  // ---- split-K accumulate ----
  #pragma unroll
  for (int fm = 0; fm < MF; ++fm)
    #pragma unroll
    for (int fn = 0; fn < NF; ++fn)
      #pragma unroll
      for (int j = 0; j < 4; ++j) {
        const int r = mt * BM + wrow * WTM + fm * 16 + lg * 4 + j;
        const int c = wcol * WTN + fn * 16 + l16;
        atomicAdd(&C[(size_t)r * ldc + c], scale * acc[fm][fn][j]);
      }

  if (FIN == 0) return;

  // ---- elect last block for this mt (release-acquire via counter RMW) ----
  __threadfence();
  __syncthreads();
  if (tid == 0) s_done = (atomicAdd(cnt + mt, 1) == kChunks - 1) ? 1 : 0;
  __syncthreads();
  if (!s_done) return;
  __threadfence();

  if (FIN == 1) {
    // dstT[c][rows[r]] = bf16(relu(C[r][c] + bias[c])), tile rows mt*64..+64
    const float* Gt = C + (size_t)(mt * BM) * ldc;
    #pragma unroll 4
    for (int rr = 0; rr < BM; ++rr) {
      float v = __hip_atomic_load(&Gt[rr * ldc + tid], __ATOMIC_RELAXED,
                                  __HIP_MEMORY_SCOPE_AGENT);
      v = fmaxf(v + bias[tid], 0.f);
      dstT[(size_t)tid * N_NODES + rows[mt * BM + rr]] = f2bf(v);
    }
  } else {
    // G3-tile = relu(C-tile) @ W2t^T ; dstT[c][rows[r]] = bf16(relu(G3 + b2[c]))
    // wave wid handles rows mt*64 + wid*16 .. +16; fragment-layout direct reads.
    const int row = mt * BM + wid * 16 + l16;
    const float* g2row = C + (size_t)row * ldc;
    f32x4 acc2[4] = {};
    #pragma unroll
    for (int ksf = 0; ksf < D_HID / 32; ++ksf) {
      const int kb = ksf * 32 + lg * 8;
      short8 af;
      #pragma unroll
      for (int e = 0; e < 8; ++e) {
        float v = __hip_atomic_load(&g2row[kb + e], __ATOMIC_RELAXED,
                                    __HIP_MEMORY_SCOPE_AGENT);
        af[e] = f2bf(fmaxf(v, 0.f));
      }
      #pragma unroll
      for (int fn = 0; fn < 4; ++fn) {
        short8 bf = *(const short8*)&W2t[(size_t)(fn * 16 + l16) * D_HID + kb];
        acc2[fn] = __builtin_amdgcn_mfma_f32_16x16x32_bf16(af, bf, acc2[fn], 0, 0, 0);
      }
    }
    #pragma unroll
    for (int fn = 0; fn < 4; ++fn) {
      const int c = fn * 16 + l16;
      const float bv = bias[c];
      #pragma unroll
      for (int j = 0; j < 4; ++j) {
        const int rrow = mt * BM + wid * 16 + lg * 4 + j;
        float v = fmaxf(acc2[fn][j] + bv, 0.f);
        dstT[(size_t)c * N_NODES + rows[rrow]] = f2bf(v);
      }
    }
  }
}

// transpose-convert weights: W1t[j][i] = bf16(W1[i][j]), W2t likewise
__global__ void conv_w_t(const float* __restrict__ W1, const float* __restrict__ W2,
                         unsigned short* __restrict__ W1t, unsigned short* __restrict__ W2t) {
  const int idx = blockIdx.x * 256 + threadIdx.x;
  if (idx < D_IN * D_HID) {
    const int j = idx / D_IN, i = idx % D_IN;
    W1t[idx] = f2bf(W1[(size_t)i * D_HID + j]);
  }
  if (idx < D_HID * D_OUT) {
    const int j = idx / D_HID, i = idx % D_HID;
    W2t[idx] = f2bf(W2[(size_t)i * D_OUT + j]);
  }
}

extern "C" void kernel_launch(void* const* d_in, const int* in_sizes, int n_in,
                              void* d_out, int out_size, void* d_ws, size_t ws_size,
                              hipStream_t stream) {
  const float* X     = (const float*)d_in[0];
  const float* A_hat = (const float*)d_in[1];
  const float* W1    = (const float*)d_in[2];
  const float* b1    = (const float*)d_in[3];
  const float* W2    = (const float*)d_in[4];
  const float* b2    = (const float*)d_in[5];
  const int*   l0    = (const int*)d_in[6];
  const int*   l1    = (const int*)d_in[7];
  float* out = (float*)d_out;

  if (ws_size < (size_t)(20u << 20)) return;
  char* ws = (char*)d_ws;
  // zeroed region: [HextT 8M][PextT 2M][G1 4M][G2 4M][cnt 4K]
  unsigned short* HextT = (unsigned short*)(ws);                      // [256][16384] 8MB
  unsigned short* PextT = (unsigned short*)(ws + (8  << 20));         // [64][16384]  2MB
  float* G1 = (float*)(ws + (10 << 20));                              // [S][256] 4MB
  float* G2 = (float*)(ws + (14 << 20));                              // [S][256] 4MB
  int*   cnt1 = (int*)(ws + (18 << 20));                              // [64]
  int*   cnt2 = cnt1 + 64;                                            // [64]
  unsigned short* W1t = (unsigned short*)(ws + (19 << 20));           // [256][512]
  unsigned short* W2t = (unsigned short*)(ws + (19 << 20) + (256 << 10)); // [64][256]

  hipMemsetAsync(ws,  0, (size_t)(18u << 20) + 4096, stream);
  hipMemsetAsync(out, 0, (size_t)N_NODES * D_OUT * 4, stream);

  conv_w_t<<<512, 256, 0, stream>>>(W1, W2, W1t, W2t);

  // L0 feature + fin1: G1 = X[l0] @ W1; HextT[:,l0[j]] = bf16(relu(G1[j]+b1))
  // M=4096 K=512 N=256, 256 blocks
  gemm_tn<64, 256, 64, false, 1><<<(S_SAMP / 64) * 4, 256, 0, stream>>>(
      X, D_IN, l0, W1t, D_IN, G1, D_HID, D_IN, 4, 1.0f,
      b1, l0, HextT, nullptr, cnt1);

  // L0 agg + fin2: G2 = 4*A_hat[l1,:] @ Hext; then per-tile
  // G3 = relu(G2tile) @ W2t^T; PextT[:,l1[j]] = bf16(relu(G3[j]+b2))
  // M=4096 K=16384 N=256, 512 blocks
  gemm_tn<64, 256, 64, false, 2><<<(S_SAMP / 64) * 8, 256, 0, stream>>>(
      A_hat, N_NODES, l1, HextT, N_NODES, G2, D_HID, N_NODES, 8, 4.0f,
      b2, l1, PextT, W2t, cnt2);

  // L1 agg: out = 4 * A_hat @ Pext   M=16384 K=16384 N=64, 2048 blocks
  gemm_tn<64, 64, 64, false, 0><<<(N_NODES / 64) * 8, 256, 0, stream>>>(
      A_hat, N_NODES, nullptr, PextT, N_NODES, out, D_OUT, N_NODES, 8, 4.0f,
      nullptr, nullptr, nullptr, nullptr, nullptr);
}